// Round 1
// baseline (206.167 us; speedup 1.0000x reference)
//
#include <hip/hip_runtime.h>
#include <float.h>

#define NS 131072
#define DD 64
#define KK 256

// d_out layout (all float32 values):
//   [0, NS)                      assignments (stored as float values)
//   [NS, 2*NS)                   min_dists
//   [2*NS, 2*NS+KK)              leaf_counts
//   [2*NS+KK, 2*NS+KK+KK*DD)     leaf_sums
//   [2*NS+KK+KK*DD, +KK)         leaf_sum_sq_dist

__global__ void zero_stats(float* __restrict__ stats, int n) {
    int i = blockIdx.x * 256 + threadIdx.x;
    if (i < n) stats[i] = 0.f;
}

__global__ __launch_bounds__(512, 2)
void deepect_main(const float* __restrict__ mb, const float* __restrict__ ctr,
                  float* __restrict__ out) {
    __shared__ float s_csq[KK];
    __shared__ float s_cnt[KK];
    __shared__ float s_ssq[KK];
    __shared__ float s_sum[KK][65];   // +1 pad: bank = (k*65+d)%32 = (k+d)%32

    const int tid = threadIdx.x;

    // zero LDS stats
    for (int idx = tid; idx < KK; idx += 512) { s_cnt[idx] = 0.f; s_ssq[idx] = 0.f; }
    for (int idx = tid; idx < KK * 65; idx += 512) ((float*)s_sum)[idx] = 0.f;

    // precompute |c_k|^2
    if (tid < KK) {
        const float4* c = (const float4*)(ctr + tid * DD);
        float acc = 0.f;
        #pragma unroll
        for (int j = 0; j < 16; ++j) {
            float4 v = c[j];
            acc += v.x * v.x + v.y * v.y + v.z * v.z + v.w * v.w;
        }
        s_csq[tid] = acc;
    }
    __syncthreads();

    const int i = blockIdx.x * 512 + tid;

    // load x row into registers, compute |x|^2
    float4 x[16];
    const float4* xr = (const float4*)(mb + (size_t)i * DD);
    float xsq = 0.f;
    #pragma unroll
    for (int j = 0; j < 16; ++j) {
        x[j] = xr[j];
        xsq += x[j].x * x[j].x + x[j].y * x[j].y + x[j].z * x[j].z + x[j].w * x[j].w;
    }

    // argmin over K centers: dist^2 = |x|^2 + |c|^2 - 2 x.c
    float best = FLT_MAX;
    int bestk = 0;
    #pragma unroll 4
    for (int k = 0; k < KK; ++k) {
        const float4* c = (const float4*)(ctr + k * DD);  // wave-uniform address
        float dot = 0.f;
        #pragma unroll
        for (int j = 0; j < 16; ++j) {
            float4 v = c[j];
            dot += x[j].x * v.x + x[j].y * v.y + x[j].z * v.z + x[j].w * v.w;
        }
        float dsq = xsq + s_csq[k] - 2.f * dot;
        if (dsq < best) { best = dsq; bestk = k; }   // strict < keeps first occurrence
    }

    float dsqc = fmaxf(best, 0.f);
    float md = sqrtf(dsqc);

    float* o_assign = out;
    float* o_mind   = out + NS;
    float* o_cnt    = out + 2 * NS;
    float* o_sum    = out + 2 * NS + KK;
    float* o_ssq    = out + 2 * NS + KK + KK * DD;

    o_assign[i] = (float)bestk;
    o_mind[i]   = md;

    // per-block LDS aggregation
    atomicAdd(&s_cnt[bestk], 1.0f);
    atomicAdd(&s_ssq[bestk], dsqc);
    #pragma unroll
    for (int j = 0; j < 16; ++j) {
        atomicAdd(&s_sum[bestk][4 * j + 0], x[j].x);
        atomicAdd(&s_sum[bestk][4 * j + 1], x[j].y);
        atomicAdd(&s_sum[bestk][4 * j + 2], x[j].z);
        atomicAdd(&s_sum[bestk][4 * j + 3], x[j].w);
    }
    __syncthreads();

    // flush block partials to global
    for (int idx = tid; idx < KK; idx += 512) {
        atomicAdd(&o_cnt[idx], s_cnt[idx]);
        atomicAdd(&o_ssq[idx], s_ssq[idx]);
    }
    for (int idx = tid; idx < KK * DD; idx += 512) {
        atomicAdd(&o_sum[idx], s_sum[idx >> 6][idx & 63]);
    }
}

extern "C" void kernel_launch(void* const* d_in, const int* in_sizes, int n_in,
                              void* d_out, int out_size, void* d_ws, size_t ws_size,
                              hipStream_t stream) {
    const float* mb  = (const float*)d_in[0];
    const float* ctr = (const float*)d_in[1];
    float* out = (float*)d_out;

    const int n_stats = KK + KK * DD + KK;  // 16896
    hipLaunchKernelGGL(zero_stats, dim3((n_stats + 255) / 256), dim3(256), 0, stream,
                       out + 2 * NS, n_stats);
    hipLaunchKernelGGL(deepect_main, dim3(NS / 512), dim3(512), 0, stream, mb, ctr, out);
}

// Round 2
// 196.947 us; speedup vs baseline: 1.0468x; 1.0468x over previous
//
#include <hip/hip_runtime.h>
#include <float.h>

#define NS 131072
#define DD 64
#define KK 256

// d_out layout (all float32 values):
//   [0, NS)                      assignments (stored as float values)
//   [NS, 2*NS)                   min_dists
//   [2*NS, 2*NS+KK)              leaf_counts
//   [2*NS+KK, 2*NS+KK+KK*DD)     leaf_sums
//   [2*NS+KK+KK*DD, +KK)         leaf_sum_sq_dist

__global__ void zero_stats(float* __restrict__ stats, int n) {
    int i = blockIdx.x * 256 + threadIdx.x;
    if (i < n) stats[i] = 0.f;
}

__global__ __launch_bounds__(512, 2)
void deepect_main(const float* __restrict__ mb, const float* __restrict__ ctr,
                  float* __restrict__ out) {
    __shared__ float s_ctr[KK][DD];   // 64 KB — centers staged once per block
    __shared__ float s_csq[KK];
    __shared__ float s_cnt[KK];
    __shared__ float s_ssq[KK];
    __shared__ float s_sum[KK][65];   // +1 pad: bank = (k+d)%32

    const int tid = threadIdx.x;

    // stage centers to LDS (coalesced float4: 4096 float4s, 8 per thread)
    for (int idx = tid; idx < KK * DD / 4; idx += 512)
        ((float4*)s_ctr)[idx] = ((const float4*)ctr)[idx];

    // zero LDS stats
    for (int idx = tid; idx < KK; idx += 512) { s_cnt[idx] = 0.f; s_ssq[idx] = 0.f; }
    for (int idx = tid; idx < KK * 65; idx += 512) ((float*)s_sum)[idx] = 0.f;

    // precompute |c_k|^2 from global (identical numerics to round 1)
    if (tid < KK) {
        const float4* c = (const float4*)(ctr + tid * DD);
        float acc = 0.f;
        #pragma unroll
        for (int j = 0; j < 16; ++j) {
            float4 v = c[j];
            acc += v.x * v.x + v.y * v.y + v.z * v.z + v.w * v.w;
        }
        s_csq[tid] = acc;
    }
    __syncthreads();

    const int i = blockIdx.x * 512 + tid;

    // load x row into registers, compute |x|^2 (kept resident: centers now
    // come from LDS so x has no residency competitor)
    float4 x[16];
    const float4* xr = (const float4*)(mb + (size_t)i * DD);
    float xsq = 0.f;
    #pragma unroll
    for (int j = 0; j < 16; ++j) {
        x[j] = xr[j];
        xsq += x[j].x * x[j].x + x[j].y * x[j].y + x[j].z * x[j].z + x[j].w * x[j].w;
    }

    // argmin over K centers: dist^2 = |x|^2 + |c|^2 - 2 x.c
    // center reads are wave-uniform LDS addresses -> broadcast ds_read_b128
    float best = FLT_MAX;
    int bestk = 0;
    #pragma unroll 2
    for (int k = 0; k < KK; ++k) {
        const float4* c = (const float4*)s_ctr[k];
        float dot = 0.f;
        #pragma unroll
        for (int j = 0; j < 16; ++j) {
            float4 v = c[j];
            dot += x[j].x * v.x + x[j].y * v.y + x[j].z * v.z + x[j].w * v.w;
        }
        float dsq = xsq + s_csq[k] - 2.f * dot;
        if (dsq < best) { best = dsq; bestk = k; }   // strict < keeps first occurrence
    }

    float dsqc = fmaxf(best, 0.f);
    float md = sqrtf(dsqc);

    float* o_assign = out;
    float* o_mind   = out + NS;
    float* o_cnt    = out + 2 * NS;
    float* o_sum    = out + 2 * NS + KK;
    float* o_ssq    = out + 2 * NS + KK + KK * DD;

    o_assign[i] = (float)bestk;
    o_mind[i]   = md;

    // per-block LDS aggregation
    atomicAdd(&s_cnt[bestk], 1.0f);
    atomicAdd(&s_ssq[bestk], dsqc);
    #pragma unroll
    for (int j = 0; j < 16; ++j) {
        atomicAdd(&s_sum[bestk][4 * j + 0], x[j].x);
        atomicAdd(&s_sum[bestk][4 * j + 1], x[j].y);
        atomicAdd(&s_sum[bestk][4 * j + 2], x[j].z);
        atomicAdd(&s_sum[bestk][4 * j + 3], x[j].w);
    }
    __syncthreads();

    // flush block partials to global
    for (int idx = tid; idx < KK; idx += 512) {
        atomicAdd(&o_cnt[idx], s_cnt[idx]);
        atomicAdd(&o_ssq[idx], s_ssq[idx]);
    }
    for (int idx = tid; idx < KK * DD; idx += 512) {
        atomicAdd(&o_sum[idx], s_sum[idx >> 6][idx & 63]);
    }
}

extern "C" void kernel_launch(void* const* d_in, const int* in_sizes, int n_in,
                              void* d_out, int out_size, void* d_ws, size_t ws_size,
                              hipStream_t stream) {
    const float* mb  = (const float*)d_in[0];
    const float* ctr = (const float*)d_in[1];
    float* out = (float*)d_out;

    const int n_stats = KK + KK * DD + KK;  // 16896
    hipLaunchKernelGGL(zero_stats, dim3((n_stats + 255) / 256), dim3(256), 0, stream,
                       out + 2 * NS, n_stats);
    hipLaunchKernelGGL(deepect_main, dim3(NS / 512), dim3(512), 0, stream, mb, ctr, out);
}

// Round 3
// 88.616 us; speedup vs baseline: 2.3265x; 2.2225x over previous
//
#include <hip/hip_runtime.h>
#include <float.h>

#define NS 131072
#define DD 64
#define KK 256
#define CPAD 72   // 64 + 8 bf16 pad -> 144B row stride, breaks stride-128 bank conflict

typedef __attribute__((ext_vector_type(8))) short bf16x8;
typedef __attribute__((ext_vector_type(4))) float f32x4;

// d_out layout (float32 values):
//   [0, NS)                      assignments (as float)
//   [NS, 2*NS)                   min_dists
//   [2*NS, 2*NS+KK)              leaf_counts
//   [2*NS+KK, +KK*DD)            leaf_sums
//   [2*NS+KK+KK*DD, +KK)         leaf_sum_sq_dist

__global__ void zero_stats(float* __restrict__ stats, int n) {
    int i = blockIdx.x * 256 + threadIdx.x;
    if (i < n) stats[i] = 0.f;
}

__device__ inline unsigned short f2bf(float f) {
    unsigned u = __float_as_uint(f);
    u += 0x7FFFu + ((u >> 16) & 1u);          // round-to-nearest-even
    return (unsigned short)(u >> 16);
}
__device__ inline float bf2f(unsigned short b) {
    return __uint_as_float(((unsigned)b) << 16);
}

__global__ __launch_bounds__(512, 2)
void deepect_main(const float* __restrict__ mb, const float* __restrict__ ctr,
                  float* __restrict__ out) {
    __shared__ __align__(16) unsigned short s_ctr[KK][CPAD];  // 36 KB
    __shared__ __align__(16) unsigned short s_x[256][CPAD];   // 36 KB
    __shared__ float s_csq[KK];
    __shared__ float s_xsq[256];
    __shared__ float s_cnt[KK];
    __shared__ float s_ssq[KK];
    __shared__ float s_sum[KK][65];                           // 66.5 KB

    const int tid  = threadIdx.x;
    const int lane = tid & 63;
    const int w    = tid >> 6;       // wave 0..7
    const int g    = lane >> 4;      // 16-lane group 0..3
    const int c16  = lane & 15;

    // ---- stage centers fp32 -> bf16 LDS (coalesced float4) ----
    for (int idx = tid; idx < KK * 16; idx += 512) {
        int row = idx >> 4, f4 = idx & 15;
        float4 v = ((const float4*)(ctr + row * DD))[f4];
        ushort4 b;
        b.x = f2bf(v.x); b.y = f2bf(v.y); b.z = f2bf(v.z); b.w = f2bf(v.w);
        *(ushort4*)&s_ctr[row][f4 * 4] = b;
    }
    // ---- zero LDS stats ----
    for (int idx = tid; idx < KK; idx += 512) { s_cnt[idx] = 0.f; s_ssq[idx] = 0.f; }
    for (int idx = tid; idx < KK * 65; idx += 512) ((float*)s_sum)[idx] = 0.f;
    __syncthreads();

    // ---- |c|^2 from bf16 values (consistent with the MFMA dot) ----
    if (tid < KK) {
        float acc = 0.f;
        #pragma unroll
        for (int j = 0; j < 16; ++j) {
            ushort4 b = *(ushort4*)&s_ctr[tid][j * 4];
            float x0 = bf2f(b.x), x1 = bf2f(b.y), x2 = bf2f(b.z), x3 = bf2f(b.w);
            acc += x0 * x0 + x1 * x1 + x2 * x2 + x3 * x3;
        }
        s_csq[tid] = acc;
    }
    __syncthreads();

    // per-lane column-half-sq-norm: csqh[t] = -csq[t*16 + c16] / 2
    float csqh[16];
    #pragma unroll
    for (int t = 0; t < 16; ++t) csqh[t] = -0.5f * s_csq[t * 16 + c16];

    float* o_assign = out;
    float* o_mind   = out + NS;
    float* o_cnt    = out + 2 * NS;
    float* o_sum    = out + 2 * NS + KK;
    float* o_ssq    = out + 2 * NS + KK + KK * DD;

    for (int ch = 0; ch < 2; ++ch) {
        __syncthreads();   // previous chunk done with s_x
        const int sbase = blockIdx.x * 512 + ch * 256;

        // ---- stage 256 sample rows fp32 -> bf16 LDS ----
        for (int idx = tid; idx < 256 * 16; idx += 512) {
            int row = idx >> 4, f4 = idx & 15;
            float4 v = ((const float4*)(mb + (size_t)(sbase + row) * DD))[f4];
            ushort4 b;
            b.x = f2bf(v.x); b.y = f2bf(v.y); b.z = f2bf(v.z); b.w = f2bf(v.w);
            *(ushort4*)&s_x[row][f4 * 4] = b;
        }
        __syncthreads();

        // ---- |x|^2 per sample (bf16-consistent) ----
        if (tid < 256) {
            float acc = 0.f;
            #pragma unroll
            for (int j = 0; j < 16; ++j) {
                ushort4 b = *(ushort4*)&s_x[tid][j * 4];
                float x0 = bf2f(b.x), x1 = bf2f(b.y), x2 = bf2f(b.z), x3 = bf2f(b.w);
                acc += x0 * x0 + x1 * x1 + x2 * x2 + x3 * x3;
            }
            s_xsq[tid] = acc;
        }
        __syncthreads();

        // ---- A fragments: 2 row-tiles x 2 K-steps, kept in VGPRs ----
        // A[row][k]: row = lane&15, k = (lane>>4)*8 + j (+32*ks)
        bf16x8 afr[2][2];
        #pragma unroll
        for (int rt = 0; rt < 2; ++rt)
            #pragma unroll
            for (int ks = 0; ks < 2; ++ks)
                afr[rt][ks] = *(bf16x8*)&s_x[w * 32 + rt * 16 + c16][g * 8 + ks * 32];

        float bestv[2][4];
        int   besti[2][4];
        #pragma unroll
        for (int rt = 0; rt < 2; ++rt)
            #pragma unroll
            for (int r = 0; r < 4; ++r) { bestv[rt][r] = -FLT_MAX; besti[rt][r] = 0; }

        // ---- 16 col-tiles of 16 centers ----
        #pragma unroll
        for (int t = 0; t < 16; ++t) {
            // B[k][col]: col = lane&15, k = (lane>>4)*8 + j (+32*ks); B[k][c] = ctr[c][k]
            bf16x8 b0 = *(bf16x8*)&s_ctr[t * 16 + c16][g * 8];
            bf16x8 b1 = *(bf16x8*)&s_ctr[t * 16 + c16][g * 8 + 32];
            const int colidx = t * 16 + c16;
            #pragma unroll
            for (int rt = 0; rt < 2; ++rt) {
                f32x4 acc;
                acc[0] = csqh[t]; acc[1] = csqh[t]; acc[2] = csqh[t]; acc[3] = csqh[t];
                acc = __builtin_amdgcn_mfma_f32_16x16x32_bf16(afr[rt][0], b0, acc, 0, 0, 0);
                acc = __builtin_amdgcn_mfma_f32_16x16x32_bf16(afr[rt][1], b1, acc, 0, 0, 0);
                // C[row][col]: col = lane&15, row = (lane>>4)*4 + r
                #pragma unroll
                for (int r = 0; r < 4; ++r) {
                    if (acc[r] > bestv[rt][r]) { bestv[rt][r] = acc[r]; besti[rt][r] = colidx; }
                }
            }
        }

        // ---- epilogue: reduce argmax over the 16-lane column group ----
        #pragma unroll
        for (int rt = 0; rt < 2; ++rt) {
            #pragma unroll
            for (int r = 0; r < 4; ++r) {
                float v = bestv[rt][r];
                int   bi = besti[rt][r];
                #pragma unroll
                for (int off = 1; off < 16; off <<= 1) {
                    float ov = __shfl_xor(v, off, 64);
                    int   oi = __shfl_xor(bi, off, 64);
                    if (ov > v || (ov == v && oi < bi)) { v = ov; bi = oi; }
                }
                const int lrow = w * 32 + rt * 16 + g * 4 + r;
                float dsq = fmaxf(s_xsq[lrow] - 2.0f * v, 0.f);
                if (c16 == 0) {
                    int s = sbase + lrow;
                    o_assign[s] = (float)bi;
                    o_mind[s]   = sqrtf(dsq);
                    atomicAdd(&s_cnt[bi], 1.0f);
                    atomicAdd(&s_ssq[bi], dsq);
                }
                // leaf_sums: 16 lanes cooperatively add this sample's 64 dims
                ushort4 xb = *(ushort4*)&s_x[lrow][c16 * 4];
                atomicAdd(&s_sum[bi][c16 * 4 + 0], bf2f(xb.x));
                atomicAdd(&s_sum[bi][c16 * 4 + 1], bf2f(xb.y));
                atomicAdd(&s_sum[bi][c16 * 4 + 2], bf2f(xb.z));
                atomicAdd(&s_sum[bi][c16 * 4 + 3], bf2f(xb.w));
            }
        }
    }

    __syncthreads();
    // ---- flush block partials to global ----
    for (int idx = tid; idx < KK; idx += 512) {
        atomicAdd(&o_cnt[idx], s_cnt[idx]);
        atomicAdd(&o_ssq[idx], s_ssq[idx]);
    }
    for (int idx = tid; idx < KK * DD; idx += 512) {
        atomicAdd(&o_sum[idx], s_sum[idx >> 6][idx & 63]);
    }
}

extern "C" void kernel_launch(void* const* d_in, const int* in_sizes, int n_in,
                              void* d_out, int out_size, void* d_ws, size_t ws_size,
                              hipStream_t stream) {
    const float* mb  = (const float*)d_in[0];
    const float* ctr = (const float*)d_in[1];
    float* out = (float*)d_out;

    const int n_stats = KK + KK * DD + KK;  // 16896
    hipLaunchKernelGGL(zero_stats, dim3((n_stats + 255) / 256), dim3(256), 0, stream,
                       out + 2 * NS, n_stats);
    hipLaunchKernelGGL(deepect_main, dim3(NS / 512), dim3(512), 0, stream, mb, ctr, out);
}